// Round 4
// baseline (259.996 us; speedup 1.0000x reference)
//
#include <hip/hip_runtime.h>

#define B_    4
#define C_    64
#define H_    160
#define W_    160
#define O_    64
#define G_    4
#define K_    9
#define CG_   16
#define MODC_ 36
#define OFFC_ 72
#define HW_   (H_*W_)

typedef __attribute__((ext_vector_type(8))) short short8;   // 8 bf16
typedef __attribute__((ext_vector_type(4))) float f32x4;

#define NCHUNK_ 18           // K=576 contraction, 32 per chunk

__device__ __forceinline__ float sigmoidf(float v) {
    return 1.0f / (1.0f + __expf(-v));
}

// round-to-nearest-even f32 -> bf16 (as short)
__device__ __forceinline__ short f2bf(float f) {
    unsigned u = __float_as_uint(f);
    u += 0x7FFFu + ((u >> 16) & 1u);
    return (short)(u >> 16);
}

// ---------------------------------------------------------------------------
// warp_ref NCHW -> grouped NHWC fp32: xt[((b*4+g)*HW + px)*16 + c]
// ---------------------------------------------------------------------------
__global__ __launch_bounds__(256) void k_nhwc(const float* __restrict__ x,
                                              float* __restrict__ xt) {
    __shared__ float lds[256][17];
    int bg   = blockIdx.x / 100;
    int pix0 = (blockIdx.x % 100) * 256;
    const float* src = x + (size_t)bg * CG_ * HW_ + pix0;
#pragma unroll
    for (int c = 0; c < CG_; ++c)
        lds[threadIdx.x][c] = src[c * HW_ + threadIdx.x];
    __syncthreads();
    float4* dst = (float4*)(xt + ((size_t)bg * HW_ + pix0 + threadIdx.x) * CG_);
#pragma unroll
    for (int q = 0; q < 4; ++q)
        dst[q] = make_float4(lds[threadIdx.x][4 * q + 0],
                             lds[threadIdx.x][4 * q + 1],
                             lds[threadIdx.x][4 * q + 2],
                             lds[threadIdx.x][4 * q + 3]);
}

// ---------------------------------------------------------------------------
// Pack weights into MFMA A-fragment order (bf16).
// ---------------------------------------------------------------------------
__global__ __launch_bounds__(256) void k_wt(const float* __restrict__ wreg,
                                            const float* __restrict__ wmod,
                                            short* __restrict__ wA_def,
                                            short* __restrict__ wA_mod) {
    int tid = blockIdx.x * 256 + threadIdx.x;
    if (tid < NCHUNK_ * 4 * 64) {
        int lane = tid & 63;
        int mt   = (tid >> 6) & 3;
        int cc   = tid >> 8;
        int quad = lane >> 4;
        int o    = mt * 16 + (lane & 15);
#pragma unroll
        for (int j = 0; j < 8; ++j) {
            int idx = cc * 32 + quad * 8 + j;
            int gk = idx >> 4, c = idx & 15;
            int g = gk / 9, kk = gk - g * 9;
            wA_def[(size_t)tid * 8 + j] = f2bf(wreg[((o * C_) + g * CG_ + c) * K_ + kk]);
        }
    } else {
        int t2 = tid - NCHUNK_ * 4 * 64;
        if (t2 < NCHUNK_ * 3 * 64) {
            int lane = t2 & 63;
            int mt   = (t2 >> 6) % 3;
            int cc   = t2 / 192;
            int quad = lane >> 4;
            int jch  = mt * 16 + (lane & 15);
#pragma unroll
            for (int j = 0; j < 8; ++j) {
                int idx = cc * 32 + quad * 8 + j;
                int t = idx >> 6, c = idx & 63;
                float v = (jch < MODC_) ? wmod[((jch * C_) + c) * K_ + t] : 0.0f;
                wA_mod[(size_t)t2 * 8 + j] = f2bf(v);
            }
        }
    }
}

// off = 80*sigmoid(offset_map) - 40
__global__ __launch_bounds__(256) void k_offsets(const float* __restrict__ om,
                                                 float* __restrict__ off) {
    int i = blockIdx.x * 256 + threadIdx.x;
    float4 v = ((const float4*)om)[i];
    float4 r;
    r.x = 80.0f * sigmoidf(v.x) - 40.0f;
    r.y = 80.0f * sigmoidf(v.y) - 40.0f;
    r.z = 80.0f * sigmoidf(v.z) - 40.0f;
    r.w = 80.0f * sigmoidf(v.w) - 40.0f;
    ((float4*)off)[i] = r;
}

// ---------------------------------------------------------------------------
// modulator conv via MFMA: D[j(48 pad), px(16)] per wave. 16 px/wave.
// ---------------------------------------------------------------------------
__global__ __launch_bounds__(256, 4) void k_mod(const float* __restrict__ xt,
                                                const short* __restrict__ wA_mod,
                                                const float* __restrict__ bm,
                                                float* __restrict__ mod) {
    int b    = (blockIdx.x & 7) >> 1;                     // XCD -> batch pin
    int tile = ((blockIdx.x >> 3) << 1) + (blockIdx.x & 1); // 0..399
    int wave = threadIdx.x >> 6;
    int lane = threadIdx.x & 63;
    int quad = lane >> 4;
    int p    = tile * 64 + wave * 16 + (lane & 15);       // pixel in [0,25600)
    int y    = p / W_;
    int x    = p - y * W_;

    f32x4 acc0 = {}, acc1 = {}, acc2 = {};

    const short8* wa = (const short8*)wA_mod;

#pragma unroll 6
    for (int cc = 0; cc < NCHUNK_; ++cc) {
        int t  = cc >> 1;
        int dy = t / 3 - 1;
        int dx = t - (t / 3) * 3 - 1;
        int yy = y + dy, xx = x + dx;
        float msk = (((unsigned)yy < (unsigned)H_) && ((unsigned)xx < (unsigned)W_)) ? 1.0f : 0.0f;
        int yc = min(max(yy, 0), H_ - 1);
        int xc = min(max(xx, 0), W_ - 1);
        int ch0 = (cc & 1) * 32 + quad * 8;               // 0..56
        int g   = ch0 >> 4;
        int cl  = ch0 & 15;
        const float4* pp = (const float4*)(xt +
            ((size_t)(b * G_ + g) * HW_ + (size_t)(yc * W_ + xc)) * CG_ + cl);
        float4 v0 = pp[0], v1 = pp[1];
        short8 bfr;
        bfr[0] = f2bf(v0.x * msk); bfr[1] = f2bf(v0.y * msk);
        bfr[2] = f2bf(v0.z * msk); bfr[3] = f2bf(v0.w * msk);
        bfr[4] = f2bf(v1.x * msk); bfr[5] = f2bf(v1.y * msk);
        bfr[6] = f2bf(v1.z * msk); bfr[7] = f2bf(v1.w * msk);

        const short8* w = wa + cc * 192;
        acc0 = __builtin_amdgcn_mfma_f32_16x16x32_bf16(w[lane],        bfr, acc0, 0, 0, 0);
        acc1 = __builtin_amdgcn_mfma_f32_16x16x32_bf16(w[64 + lane],   bfr, acc1, 0, 0, 0);
        acc2 = __builtin_amdgcn_mfma_f32_16x16x32_bf16(w[128 + lane],  bfr, acc2, 0, 0, 0);
    }

    // D: row(j') = quad*4 + reg, col(px) = lane&15
    float* mp = mod + (size_t)b * MODC_ * HW_ + p;
#pragma unroll
    for (int reg = 0; reg < 4; ++reg) {
        int j0 = quad * 4 + reg;
        mp[(size_t)j0 * HW_]        = 2.0f * sigmoidf(acc0[reg] + bm[j0]);
        mp[(size_t)(16 + j0) * HW_] = 2.0f * sigmoidf(acc1[reg] + bm[16 + j0]);
        int j2 = 32 + j0;
        if (j2 < MODC_)
            mp[(size_t)j2 * HW_] = 2.0f * sigmoidf(acc2[reg] + bm[j2]);
    }
}

// ---------------------------------------------------------------------------
// deformable conv via MFMA: D[o(64), px(16)] per wave. 3 super-chunks of 6:
// hoisted offset/mod loads (18 loads in flight), then 6 unrolled gather+MFMA
// bodies so many dwordx4 gathers overlap.
// ---------------------------------------------------------------------------
__global__ __launch_bounds__(256, 4) void k_deform(const float* __restrict__ xt,
                                                   const float* __restrict__ off,
                                                   const float* __restrict__ mod,
                                                   const short* __restrict__ wA_def,
                                                   float* __restrict__ out) {
    int b    = (blockIdx.x & 7) >> 1;
    int tile = ((blockIdx.x >> 3) << 1) + (blockIdx.x & 1);
    int wave = threadIdx.x >> 6;
    int lane = threadIdx.x & 63;
    int quad = lane >> 4;
    int p    = tile * 64 + wave * 16 + (lane & 15);
    int y    = p / W_;
    int x    = p - y * W_;

    f32x4 acc0 = {}, acc1 = {}, acc2 = {}, acc3 = {};

    const float* offp = off + (size_t)b * OFFC_ * HW_ + p;
    const float* modp = mod + (size_t)b * MODC_ * HW_ + p;
    const short8* wa  = (const short8*)wA_def;
    int cbase = (quad & 1) * 8;

#pragma unroll 1
    for (int sc = 0; sc < 3; ++sc) {
        float oyv[6], oxv[6], fmv[6];
#pragma unroll
        for (int u = 0; u < 6; ++u) {
            int cc = sc * 6 + u;
            int gk = cc * 2 + (quad >> 1);
            int g  = gk / 9;
            int kk = gk - g * 9;
            oyv[u] = offp[(size_t)(g * 18 + kk * 2) * HW_];
            oxv[u] = offp[(size_t)(g * 18 + kk * 2 + 1) * HW_];
            fmv[u] = modp[(size_t)gk * HW_];
        }
#pragma unroll
        for (int u = 0; u < 6; ++u) {
            int cc = sc * 6 + u;
            int gk = cc * 2 + (quad >> 1);
            int g  = gk / 9;
            int kk = gk - g * 9;
            int ki = kk / 3;
            int kj = kk - ki * 3;

            float py  = oyv[u] + (float)(y - 1 + ki);
            float pxf = oxv[u] + (float)(x - 1 + kj);
            float y0f = floorf(py), x0f = floorf(pxf);
            float wy  = py - y0f,   wx  = pxf - x0f;
            int y0 = (int)y0f, x0i = (int)x0f;
            int y1 = y0 + 1,   x1  = x0i + 1;
            float vy0 = ((unsigned)y0  < (unsigned)H_) ? 1.0f : 0.0f;
            float vy1 = ((unsigned)y1  < (unsigned)H_) ? 1.0f : 0.0f;
            float vx0 = ((unsigned)x0i < (unsigned)W_) ? 1.0f : 0.0f;
            float vx1 = ((unsigned)x1  < (unsigned)W_) ? 1.0f : 0.0f;
            int yc0 = min(max(y0, 0), H_ - 1);
            int yc1 = min(max(y1, 0), H_ - 1);
            int xc0 = min(max(x0i, 0), W_ - 1);
            int xc1 = min(max(x1, 0), W_ - 1);

            float fm  = fmv[u];
            float w00 = (1.0f - wy) * (1.0f - wx) * vy0 * vx0 * fm;
            float w01 = (1.0f - wy) * wx          * vy0 * vx1 * fm;
            float w10 = wy          * (1.0f - wx) * vy1 * vx0 * fm;
            float w11 = wy          * wx          * vy1 * vx1 * fm;

            const float* xg = xt + ((size_t)(b * G_ + g) * HW_) * CG_ + cbase;
            const float4* p00 = (const float4*)(xg + (size_t)(yc0 * W_ + xc0) * CG_);
            const float4* p01 = (const float4*)(xg + (size_t)(yc0 * W_ + xc1) * CG_);
            const float4* p10 = (const float4*)(xg + (size_t)(yc1 * W_ + xc0) * CG_);
            const float4* p11 = (const float4*)(xg + (size_t)(yc1 * W_ + xc1) * CG_);

            float4 a0 = p00[0], a1 = p00[1];
            float4 b0 = p01[0], b1 = p01[1];
            float4 c0 = p10[0], c1 = p10[1];
            float4 d0 = p11[0], d1 = p11[1];

            short8 bfr;
            bfr[0] = f2bf(fmaf(w00, a0.x, fmaf(w01, b0.x, fmaf(w10, c0.x, w11 * d0.x))));
            bfr[1] = f2bf(fmaf(w00, a0.y, fmaf(w01, b0.y, fmaf(w10, c0.y, w11 * d0.y))));
            bfr[2] = f2bf(fmaf(w00, a0.z, fmaf(w01, b0.z, fmaf(w10, c0.z, w11 * d0.z))));
            bfr[3] = f2bf(fmaf(w00, a0.w, fmaf(w01, b0.w, fmaf(w10, c0.w, w11 * d0.w))));
            bfr[4] = f2bf(fmaf(w00, a1.x, fmaf(w01, b1.x, fmaf(w10, c1.x, w11 * d1.x))));
            bfr[5] = f2bf(fmaf(w00, a1.y, fmaf(w01, b1.y, fmaf(w10, c1.y, w11 * d1.y))));
            bfr[6] = f2bf(fmaf(w00, a1.z, fmaf(w01, b1.z, fmaf(w10, c1.z, w11 * d1.z))));
            bfr[7] = f2bf(fmaf(w00, a1.w, fmaf(w01, b1.w, fmaf(w10, c1.w, w11 * d1.w))));

            const short8* w = wa + cc * 256;
            acc0 = __builtin_amdgcn_mfma_f32_16x16x32_bf16(w[lane],        bfr, acc0, 0, 0, 0);
            acc1 = __builtin_amdgcn_mfma_f32_16x16x32_bf16(w[64 + lane],   bfr, acc1, 0, 0, 0);
            acc2 = __builtin_amdgcn_mfma_f32_16x16x32_bf16(w[128 + lane],  bfr, acc2, 0, 0, 0);
            acc3 = __builtin_amdgcn_mfma_f32_16x16x32_bf16(w[192 + lane],  bfr, acc3, 0, 0, 0);
        }
    }

    // D: row(o') = quad*4 + reg, col(px) = lane&15
    float* op = out + (size_t)b * O_ * HW_ + p;
#pragma unroll
    for (int reg = 0; reg < 4; ++reg) {
        int o0 = quad * 4 + reg;
        op[(size_t)o0 * HW_]        = acc0[reg];
        op[(size_t)(16 + o0) * HW_] = acc1[reg];
        op[(size_t)(32 + o0) * HW_] = acc2[reg];
        op[(size_t)(48 + o0) * HW_] = acc3[reg];
    }
}

extern "C" void kernel_launch(void* const* d_in, const int* in_sizes, int n_in,
                              void* d_out, int out_size, void* d_ws, size_t ws_size,
                              hipStream_t stream) {
    const float* warp = (const float*)d_in[0];
    const float* omap = (const float*)d_in[1];
    const float* wreg = (const float*)d_in[2];
    const float* wmod = (const float*)d_in[3];
    const float* bmod = (const float*)d_in[4];

    float* out     = (float*)d_out;                    // (4,64,160,160)
    float* out_off = out + (size_t)B_ * O_ * HW_;      // (4,72,160,160)

    float* mod    = (float*)d_ws;                      // 14.75 MB
    float* xt     = mod + (size_t)B_ * MODC_ * HW_;    // 26.2 MB
    short* wA_def = (short*)(xt + (size_t)B_ * C_ * HW_);   // 18*4*64*8 bf16
    short* wA_mod = wA_def + NCHUNK_ * 4 * 64 * 8;          // 18*3*64*8 bf16

    hipLaunchKernelGGL(k_nhwc, dim3(16 * 100), dim3(256), 0, stream, warp, xt);
    hipLaunchKernelGGL(k_wt, dim3(32), dim3(256), 0, stream,
                       wreg, wmod, wA_def, wA_mod);
    hipLaunchKernelGGL(k_offsets, dim3((B_ * OFFC_ * HW_ / 4) / 256), dim3(256),
                       0, stream, omap, out_off);
    hipLaunchKernelGGL(k_mod, dim3(1600), dim3(256), 0, stream,
                       xt, wA_mod, bmod, mod);
    hipLaunchKernelGGL(k_deform, dim3(1600), dim3(256), 0, stream,
                       xt, out_off, mod, wA_def, out);
}

// Round 5
// 202.490 us; speedup vs baseline: 1.2840x; 1.2840x over previous
//
#include <hip/hip_runtime.h>

#define B_    4
#define C_    64
#define H_    160
#define W_    160
#define O_    64
#define G_    4
#define K_    9
#define CG_   16
#define MODC_ 36
#define OFFC_ 72
#define HW_   (H_*W_)

typedef __attribute__((ext_vector_type(8))) short short8;   // 8 bf16
typedef __attribute__((ext_vector_type(4))) float f32x4;

#define NCHUNK_ 18           // K=576 contraction, 32 per chunk

__device__ __forceinline__ float sigmoidf(float v) {
    return 1.0f / (1.0f + __expf(-v));
}

// round-to-nearest-even f32 -> bf16 (as short)
__device__ __forceinline__ short f2bf(float f) {
    unsigned u = __float_as_uint(f);
    u += 0x7FFFu + ((u >> 16) & 1u);
    return (short)(u >> 16);
}

__device__ __forceinline__ float bf2f(short s) {
    return __uint_as_float(((unsigned)(unsigned short)s) << 16);
}

// ---------------------------------------------------------------------------
// k_prep: one dispatch doing three independent jobs (branch on blockIdx):
//   [0,1600)    : warp_ref NCHW fp32 -> grouped NHWC bf16 xt[(bg*HW+px)*16+c]
//   [1600,8800) : out_off = 80*sigmoid(offset_map) - 40
//   [8800,8832) : pack w_reg / w_mod into MFMA A-fragment order (bf16)
// ---------------------------------------------------------------------------
__global__ __launch_bounds__(256) void k_prep(const float* __restrict__ x,
                                              const float* __restrict__ omap,
                                              const float* __restrict__ wreg,
                                              const float* __restrict__ wmod,
                                              unsigned short* __restrict__ xt,
                                              short* __restrict__ wA_def,
                                              short* __restrict__ wA_mod,
                                              float* __restrict__ out_off) {
    int blk = blockIdx.x;
    if (blk < 1600) {
        __shared__ unsigned short lds[256][17];
        int bg   = blk / 100;
        int pix0 = (blk % 100) * 256;
        const float* src = x + (size_t)bg * CG_ * HW_ + pix0;
#pragma unroll
        for (int c = 0; c < CG_; ++c)
            lds[threadIdx.x][c] = (unsigned short)f2bf(src[c * HW_ + threadIdx.x]);
        __syncthreads();
        unsigned w[8];
#pragma unroll
        for (int q = 0; q < 8; ++q)
            w[q] = (unsigned)lds[threadIdx.x][2 * q] |
                   ((unsigned)lds[threadIdx.x][2 * q + 1] << 16);
        uint4* dst = (uint4*)(xt + ((size_t)bg * HW_ + pix0 + threadIdx.x) * CG_);
        dst[0] = make_uint4(w[0], w[1], w[2], w[3]);
        dst[1] = make_uint4(w[4], w[5], w[6], w[7]);
    } else if (blk < 8800) {
        int i = (blk - 1600) * 256 + threadIdx.x;
        float4 v = ((const float4*)omap)[i];
        float4 r;
        r.x = 80.0f * sigmoidf(v.x) - 40.0f;
        r.y = 80.0f * sigmoidf(v.y) - 40.0f;
        r.z = 80.0f * sigmoidf(v.z) - 40.0f;
        r.w = 80.0f * sigmoidf(v.w) - 40.0f;
        ((float4*)out_off)[i] = r;
    } else {
        int tid = (blk - 8800) * 256 + threadIdx.x;
        if (tid < NCHUNK_ * 4 * 64) {
            int lane = tid & 63;
            int mt   = (tid >> 6) & 3;
            int cc   = tid >> 8;
            int quad = lane >> 4;
            int o    = mt * 16 + (lane & 15);
#pragma unroll
            for (int j = 0; j < 8; ++j) {
                int idx = cc * 32 + quad * 8 + j;
                int gk = idx >> 4, c = idx & 15;
                int g = gk / 9, kk = gk - g * 9;
                wA_def[(size_t)tid * 8 + j] = f2bf(wreg[((o * C_) + g * CG_ + c) * K_ + kk]);
            }
        } else {
            int t2 = tid - NCHUNK_ * 4 * 64;
            if (t2 < NCHUNK_ * 3 * 64) {
                int lane = t2 & 63;
                int mt   = (t2 >> 6) % 3;
                int cc   = t2 / 192;
                int quad = lane >> 4;
                int jch  = mt * 16 + (lane & 15);
#pragma unroll
                for (int j = 0; j < 8; ++j) {
                    int idx = cc * 32 + quad * 8 + j;
                    int t = idx >> 6, c = idx & 63;
                    float v = (jch < MODC_) ? wmod[((jch * C_) + c) * K_ + t] : 0.0f;
                    wA_mod[(size_t)t2 * 8 + j] = f2bf(v);
                }
            }
        }
    }
}

// ---------------------------------------------------------------------------
// k_fused: phase A computes the modulator for this wave's 16 pixels via MFMA
// (result -> LDS, 9 KB), phase B does the deformable conv via MFMA with
// bf16 gathers (4 x 16B per chunk-lane).
// ---------------------------------------------------------------------------
__global__ __launch_bounds__(256, 4) void k_fused(const unsigned short* __restrict__ xt,
                                                  const float* __restrict__ out_off,
                                                  const short* __restrict__ wA_mod,
                                                  const short* __restrict__ wA_def,
                                                  const float* __restrict__ bm,
                                                  float* __restrict__ out) {
    __shared__ float modl[4][MODC_][16];
    int b    = (blockIdx.x & 7) >> 1;                        // XCD -> batch pin
    int tile = ((blockIdx.x >> 3) << 1) + (blockIdx.x & 1);  // 0..399
    int wave = threadIdx.x >> 6;
    int lane = threadIdx.x & 63;
    int quad = lane >> 4;
    int px   = lane & 15;
    int p    = tile * 64 + wave * 16 + px;
    int y    = p / W_;
    int x    = p - y * W_;

    // ---------------- phase A: modulator ----------------
    f32x4 m0 = {}, m1 = {}, m2 = {};
    const short8* wm = (const short8*)wA_mod;

#pragma unroll 6
    for (int cc = 0; cc < NCHUNK_; ++cc) {
        int t  = cc >> 1;
        int dy = t / 3 - 1;
        int dx = t - (t / 3) * 3 - 1;
        int yy = y + dy, xx = x + dx;
        bool ok = (((unsigned)yy < (unsigned)H_) && ((unsigned)xx < (unsigned)W_));
        int yc = min(max(yy, 0), H_ - 1);
        int xc = min(max(xx, 0), W_ - 1);
        int ch0 = (cc & 1) * 32 + quad * 8;
        int g   = ch0 >> 4;
        int cl  = ch0 & 15;
        int4 raw = *(const int4*)(xt + ((size_t)(b * G_ + g) * HW_ +
                                        (size_t)(yc * W_ + xc)) * CG_ + cl);
        if (!ok) raw = make_int4(0, 0, 0, 0);
        short8 bfr = *(short8*)&raw;

        const short8* w = wm + cc * 192;
        m0 = __builtin_amdgcn_mfma_f32_16x16x32_bf16(w[lane],       bfr, m0, 0, 0, 0);
        m1 = __builtin_amdgcn_mfma_f32_16x16x32_bf16(w[64 + lane],  bfr, m1, 0, 0, 0);
        m2 = __builtin_amdgcn_mfma_f32_16x16x32_bf16(w[128 + lane], bfr, m2, 0, 0, 0);
    }

    float* ml = &modl[wave][0][0];
#pragma unroll
    for (int reg = 0; reg < 4; ++reg) {
        int j0 = quad * 4 + reg;
        ml[j0 * 16 + px]        = 2.0f * sigmoidf(m0[reg] + bm[j0]);
        ml[(16 + j0) * 16 + px] = 2.0f * sigmoidf(m1[reg] + bm[16 + j0]);
        if (32 + j0 < MODC_)
            ml[(32 + j0) * 16 + px] = 2.0f * sigmoidf(m2[reg] + bm[32 + j0]);
    }
    __syncthreads();

    // ---------------- phase B: deformable conv ----------------
    f32x4 acc0 = {}, acc1 = {}, acc2 = {}, acc3 = {};
    const float* offp = out_off + (size_t)b * OFFC_ * HW_ + p;
    const short8* wa  = (const short8*)wA_def;
    int cbase = (quad & 1) * 8;

#pragma unroll 1
    for (int sc = 0; sc < 3; ++sc) {
        float oyv[6], oxv[6], fmv[6];
#pragma unroll
        for (int u = 0; u < 6; ++u) {
            int cc = sc * 6 + u;
            int gk = cc * 2 + (quad >> 1);
            int g  = gk / 9;
            int kk = gk - g * 9;
            oyv[u] = offp[(size_t)(g * 18 + kk * 2) * HW_];
            oxv[u] = offp[(size_t)(g * 18 + kk * 2 + 1) * HW_];
            fmv[u] = ml[gk * 16 + px];
        }
#pragma unroll
        for (int u = 0; u < 6; ++u) {
            int cc = sc * 6 + u;
            int gk = cc * 2 + (quad >> 1);
            int g  = gk / 9;
            int kk = gk - g * 9;
            int ki = kk / 3;
            int kj = kk - ki * 3;

            float py  = oyv[u] + (float)(y - 1 + ki);
            float pxf = oxv[u] + (float)(x - 1 + kj);
            float y0f = floorf(py), x0f = floorf(pxf);
            float wy  = py - y0f,   wx  = pxf - x0f;
            int y0 = (int)y0f, x0i = (int)x0f;
            int y1 = y0 + 1,   x1  = x0i + 1;
            float vy0 = ((unsigned)y0  < (unsigned)H_) ? 1.0f : 0.0f;
            float vy1 = ((unsigned)y1  < (unsigned)H_) ? 1.0f : 0.0f;
            float vx0 = ((unsigned)x0i < (unsigned)W_) ? 1.0f : 0.0f;
            float vx1 = ((unsigned)x1  < (unsigned)W_) ? 1.0f : 0.0f;
            int yc0 = min(max(y0, 0), H_ - 1);
            int yc1 = min(max(y1, 0), H_ - 1);
            int xc0 = min(max(x0i, 0), W_ - 1);
            int xc1 = min(max(x1, 0), W_ - 1);

            float fm  = fmv[u];
            float w00 = (1.0f - wy) * (1.0f - wx) * vy0 * vx0 * fm;
            float w01 = (1.0f - wy) * wx          * vy0 * vx1 * fm;
            float w10 = wy          * (1.0f - wx) * vy1 * vx0 * fm;
            float w11 = wy          * wx          * vy1 * vx1 * fm;

            const unsigned short* xg = xt + ((size_t)(b * G_ + g) * HW_) * CG_ + cbase;
            short8 s00 = *(const short8*)(xg + (size_t)(yc0 * W_ + xc0) * CG_);
            short8 s01 = *(const short8*)(xg + (size_t)(yc0 * W_ + xc1) * CG_);
            short8 s10 = *(const short8*)(xg + (size_t)(yc1 * W_ + xc0) * CG_);
            short8 s11 = *(const short8*)(xg + (size_t)(yc1 * W_ + xc1) * CG_);

            short8 bfr;
#pragma unroll
            for (int i = 0; i < 8; ++i) {
                float v = fmaf(w00, bf2f(s00[i]),
                          fmaf(w01, bf2f(s01[i]),
                          fmaf(w10, bf2f(s10[i]), w11 * bf2f(s11[i]))));
                bfr[i] = f2bf(v);
            }

            const short8* w = wa + cc * 256;
            acc0 = __builtin_amdgcn_mfma_f32_16x16x32_bf16(w[lane],       bfr, acc0, 0, 0, 0);
            acc1 = __builtin_amdgcn_mfma_f32_16x16x32_bf16(w[64 + lane],  bfr, acc1, 0, 0, 0);
            acc2 = __builtin_amdgcn_mfma_f32_16x16x32_bf16(w[128 + lane], bfr, acc2, 0, 0, 0);
            acc3 = __builtin_amdgcn_mfma_f32_16x16x32_bf16(w[192 + lane], bfr, acc3, 0, 0, 0);
        }
    }

    // D: row(o') = quad*4 + reg, col(px) = lane&15
    float* op = out + (size_t)b * O_ * HW_ + p;
#pragma unroll
    for (int reg = 0; reg < 4; ++reg) {
        int o0 = quad * 4 + reg;
        op[(size_t)o0 * HW_]        = acc0[reg];
        op[(size_t)(16 + o0) * HW_] = acc1[reg];
        op[(size_t)(32 + o0) * HW_] = acc2[reg];
        op[(size_t)(48 + o0) * HW_] = acc3[reg];
    }
}

extern "C" void kernel_launch(void* const* d_in, const int* in_sizes, int n_in,
                              void* d_out, int out_size, void* d_ws, size_t ws_size,
                              hipStream_t stream) {
    const float* warp = (const float*)d_in[0];
    const float* omap = (const float*)d_in[1];
    const float* wreg = (const float*)d_in[2];
    const float* wmod = (const float*)d_in[3];
    const float* bmod = (const float*)d_in[4];

    float* out     = (float*)d_out;                    // (4,64,160,160)
    float* out_off = out + (size_t)B_ * O_ * HW_;      // (4,72,160,160)

    unsigned short* xt = (unsigned short*)d_ws;                  // 13.1 MB bf16
    short* wA_def = (short*)(xt + (size_t)B_ * C_ * HW_);        // 36864 bf16
    short* wA_mod = wA_def + NCHUNK_ * 4 * 64 * 8;               // 27648 bf16

    hipLaunchKernelGGL(k_prep, dim3(8832), dim3(256), 0, stream,
                       warp, omap, wreg, wmod, xt, wA_def, wA_mod, out_off);
    hipLaunchKernelGGL(k_fused, dim3(1600), dim3(256), 0, stream,
                       xt, out_off, wA_mod, wA_def, bmod, out);
}

// Round 6
// 189.223 us; speedup vs baseline: 1.3740x; 1.0701x over previous
//
#include <hip/hip_runtime.h>

#define B_    4
#define C_    64
#define H_    160
#define W_    160
#define O_    64
#define G_    4
#define K_    9
#define CG_   16
#define MODC_ 36
#define OFFC_ 72
#define HW_   (H_*W_)

typedef __attribute__((ext_vector_type(8))) short short8;   // 8 bf16
typedef __attribute__((ext_vector_type(4))) float f32x4;
typedef __attribute__((ext_vector_type(2))) float f32x2;

#define NCHUNK_ 18           // K=576 contraction, 32 per chunk

__device__ __forceinline__ float sigmoidf(float v) {
    return 1.0f / (1.0f + __expf(-v));
}

// round-to-nearest-even f32 -> bf16 (as short) — used in cold paths
__device__ __forceinline__ short f2bf(float f) {
    unsigned u = __float_as_uint(f);
    u += 0x7FFFu + ((u >> 16) & 1u);
    return (short)(u >> 16);
}

// unpack 2 bf16 (in one u32) -> packed float2
__device__ __forceinline__ f32x2 unpk(unsigned u) {
    f32x2 r;
    r.x = __uint_as_float(u << 16);
    r.y = __uint_as_float(u & 0xffff0000u);
    return r;
}

// round-half-up pack of two f32 -> two bf16 in one u32 (lo = a)
__device__ __forceinline__ unsigned pack2(float a, float b) {
    unsigned ua = __float_as_uint(a) + 0x8000u;
    unsigned ub = __float_as_uint(b) + 0x8000u;
#if __has_builtin(__builtin_amdgcn_perm)
    return __builtin_amdgcn_perm(ub, ua, 0x07060302u); // D.b0=ua.b2 D.b1=ua.b3 D.b2=ub.b2 D.b3=ub.b3
#else
    return (ua >> 16) | (ub & 0xffff0000u);
#endif
}

// bilinear combine of 2 channels (one u32 per corner), packed math
__device__ __forceinline__ unsigned comb2(int a, int b, int c, int d,
                                          f32x2 w0, f32x2 w1, f32x2 w2, f32x2 w3) {
    f32x2 v = w0 * unpk((unsigned)a) + w1 * unpk((unsigned)b)
            + w2 * unpk((unsigned)c) + w3 * unpk((unsigned)d);
    return pack2(v.x, v.y);
}

// ---------------------------------------------------------------------------
// k_prep: one dispatch doing three independent jobs (branch on blockIdx):
//   [0,1600)    : warp_ref NCHW fp32 -> grouped NHWC bf16 xt[(bg*HW+px)*16+c]
//   [1600,8800) : out_off = 80*sigmoid(offset_map) - 40
//   [8800,8832) : pack w_reg / w_mod into MFMA A-fragment order (bf16)
// ---------------------------------------------------------------------------
__global__ __launch_bounds__(256) void k_prep(const float* __restrict__ x,
                                              const float* __restrict__ omap,
                                              const float* __restrict__ wreg,
                                              const float* __restrict__ wmod,
                                              unsigned short* __restrict__ xt,
                                              short* __restrict__ wA_def,
                                              short* __restrict__ wA_mod,
                                              float* __restrict__ out_off) {
    int blk = blockIdx.x;
    if (blk < 1600) {
        __shared__ unsigned short lds[256][17];
        int bg   = blk / 100;
        int pix0 = (blk % 100) * 256;
        const float* src = x + (size_t)bg * CG_ * HW_ + pix0;
#pragma unroll
        for (int c = 0; c < CG_; ++c)
            lds[threadIdx.x][c] = (unsigned short)f2bf(src[c * HW_ + threadIdx.x]);
        __syncthreads();
        unsigned w[8];
#pragma unroll
        for (int q = 0; q < 8; ++q)
            w[q] = (unsigned)lds[threadIdx.x][2 * q] |
                   ((unsigned)lds[threadIdx.x][2 * q + 1] << 16);
        uint4* dst = (uint4*)(xt + ((size_t)bg * HW_ + pix0 + threadIdx.x) * CG_);
        dst[0] = make_uint4(w[0], w[1], w[2], w[3]);
        dst[1] = make_uint4(w[4], w[5], w[6], w[7]);
    } else if (blk < 8800) {
        int i = (blk - 1600) * 256 + threadIdx.x;
        float4 v = ((const float4*)omap)[i];
        float4 r;
        r.x = 80.0f * sigmoidf(v.x) - 40.0f;
        r.y = 80.0f * sigmoidf(v.y) - 40.0f;
        r.z = 80.0f * sigmoidf(v.z) - 40.0f;
        r.w = 80.0f * sigmoidf(v.w) - 40.0f;
        ((float4*)out_off)[i] = r;
    } else {
        int tid = (blk - 8800) * 256 + threadIdx.x;
        if (tid < NCHUNK_ * 4 * 64) {
            int lane = tid & 63;
            int mt   = (tid >> 6) & 3;
            int cc   = tid >> 8;
            int quad = lane >> 4;
            int o    = mt * 16 + (lane & 15);
#pragma unroll
            for (int j = 0; j < 8; ++j) {
                int idx = cc * 32 + quad * 8 + j;
                int gk = idx >> 4, c = idx & 15;
                int g = gk / 9, kk = gk - g * 9;
                wA_def[(size_t)tid * 8 + j] = f2bf(wreg[((o * C_) + g * CG_ + c) * K_ + kk]);
            }
        } else {
            int t2 = tid - NCHUNK_ * 4 * 64;
            if (t2 < NCHUNK_ * 3 * 64) {
                int lane = t2 & 63;
                int mt   = (t2 >> 6) % 3;
                int cc   = t2 / 192;
                int quad = lane >> 4;
                int jch  = mt * 16 + (lane & 15);
#pragma unroll
                for (int j = 0; j < 8; ++j) {
                    int idx = cc * 32 + quad * 8 + j;
                    int t = idx >> 6, c = idx & 63;
                    float v = (jch < MODC_) ? wmod[((jch * C_) + c) * K_ + t] : 0.0f;
                    wA_mod[(size_t)t2 * 8 + j] = f2bf(v);
                }
            }
        }
    }
}

// ---------------------------------------------------------------------------
// k_fused: phase A modulator MFMA -> wave-private LDS slice (no barrier),
// phase B deformable conv MFMA with a 2-stage software pipeline: chunk cc+1's
// 4 corner-gathers are in flight while chunk cc packs + MFMAs.
// ---------------------------------------------------------------------------

#define PREPB(cc_, par_) do {                                                  \
    int gk = (cc_) * 2 + qh;                                                   \
    int g  = gk / 9, kk = gk - g * 9;                                          \
    int ki = kk / 3, kj = kk - ki * 3;                                         \
    float fm = ml[gk * 16 + px];                                               \
    float py  = oy[cc_] + (float)(y - 1 + ki);                                 \
    float pxf = ox[cc_] + (float)(x - 1 + kj);                                 \
    float y0f = floorf(py), x0f = floorf(pxf);                                 \
    float wy = py - y0f, wx = pxf - x0f;                                       \
    int y0 = (int)y0f, x0i = (int)x0f;                                         \
    int y1 = y0 + 1, x1 = x0i + 1;                                             \
    float vy0 = ((unsigned)y0  < (unsigned)H_) ? 1.0f : 0.0f;                  \
    float vy1 = ((unsigned)y1  < (unsigned)H_) ? 1.0f : 0.0f;                  \
    float vx0 = ((unsigned)x0i < (unsigned)W_) ? 1.0f : 0.0f;                  \
    float vx1 = ((unsigned)x1  < (unsigned)W_) ? 1.0f : 0.0f;                  \
    int yc0 = min(max(y0, 0), H_ - 1);                                         \
    int yc1 = min(max(y1, 0), H_ - 1);                                         \
    int xc0 = min(max(x0i, 0), W_ - 1);                                        \
    int xc1 = min(max(x1, 0), W_ - 1);                                         \
    cw[par_][0] = (1.0f - wy) * (1.0f - wx) * vy0 * vx0 * fm;                  \
    cw[par_][1] = (1.0f - wy) * wx          * vy0 * vx1 * fm;                  \
    cw[par_][2] = wy * (1.0f - wx) * vy1 * vx0 * fm;                           \
    cw[par_][3] = wy * wx          * vy1 * vx1 * fm;                           \
    const unsigned short* xg = xt + ((size_t)(b * G_ + g) * HW_) * CG_ + cbase;\
    G[par_][0] = *(const int4*)(xg + (size_t)(yc0 * W_ + xc0) * CG_);          \
    G[par_][1] = *(const int4*)(xg + (size_t)(yc0 * W_ + xc1) * CG_);          \
    G[par_][2] = *(const int4*)(xg + (size_t)(yc1 * W_ + xc0) * CG_);          \
    G[par_][3] = *(const int4*)(xg + (size_t)(yc1 * W_ + xc1) * CG_);          \
} while (0)

#define CONSB(cc_, par_) do {                                                  \
    f32x2 w0 = {cw[par_][0], cw[par_][0]};                                     \
    f32x2 w1 = {cw[par_][1], cw[par_][1]};                                     \
    f32x2 w2 = {cw[par_][2], cw[par_][2]};                                     \
    f32x2 w3 = {cw[par_][3], cw[par_][3]};                                     \
    int4 bi;                                                                   \
    bi.x = (int)comb2(G[par_][0].x, G[par_][1].x, G[par_][2].x, G[par_][3].x,  \
                      w0, w1, w2, w3);                                         \
    bi.y = (int)comb2(G[par_][0].y, G[par_][1].y, G[par_][2].y, G[par_][3].y,  \
                      w0, w1, w2, w3);                                         \
    bi.z = (int)comb2(G[par_][0].z, G[par_][1].z, G[par_][2].z, G[par_][3].z,  \
                      w0, w1, w2, w3);                                         \
    bi.w = (int)comb2(G[par_][0].w, G[par_][1].w, G[par_][2].w, G[par_][3].w,  \
                      w0, w1, w2, w3);                                         \
    short8 bfr = *(short8*)&bi;                                                \
    const short8* wp = wa + (cc_) * 256;                                       \
    acc0 = __builtin_amdgcn_mfma_f32_16x16x32_bf16(wp[lane],       bfr, acc0, 0, 0, 0); \
    acc1 = __builtin_amdgcn_mfma_f32_16x16x32_bf16(wp[64 + lane],  bfr, acc1, 0, 0, 0); \
    acc2 = __builtin_amdgcn_mfma_f32_16x16x32_bf16(wp[128 + lane], bfr, acc2, 0, 0, 0); \
    acc3 = __builtin_amdgcn_mfma_f32_16x16x32_bf16(wp[192 + lane], bfr, acc3, 0, 0, 0); \
} while (0)

__global__ __launch_bounds__(256, 4) void k_fused(const unsigned short* __restrict__ xt,
                                                  const float* __restrict__ out_off,
                                                  const short* __restrict__ wA_mod,
                                                  const short* __restrict__ wA_def,
                                                  const float* __restrict__ bm,
                                                  float* __restrict__ out) {
    __shared__ float modl[4][MODC_][16];
    int b    = (blockIdx.x & 7) >> 1;                        // XCD -> batch pin
    int tile = ((blockIdx.x >> 3) << 1) + (blockIdx.x & 1);  // 0..399
    int wave = threadIdx.x >> 6;
    int lane = threadIdx.x & 63;
    int quad = lane >> 4;
    int px   = lane & 15;
    int p    = tile * 64 + wave * 16 + px;
    int y    = p / W_;
    int x    = p - y * W_;

    // ---------------- phase A: modulator (wave-private LDS slice) -----------
    f32x4 m0 = {}, m1 = {}, m2 = {};
    const short8* wm = (const short8*)wA_mod;

#pragma unroll
    for (int cc = 0; cc < NCHUNK_; ++cc) {
        int t  = cc >> 1;
        int dy = t / 3 - 1;
        int dx = t - (t / 3) * 3 - 1;
        int yy = y + dy, xx = x + dx;
        bool ok = (((unsigned)yy < (unsigned)H_) && ((unsigned)xx < (unsigned)W_));
        int yc = min(max(yy, 0), H_ - 1);
        int xc = min(max(xx, 0), W_ - 1);
        int ch0 = (cc & 1) * 32 + (quad << 3);
        int g   = ch0 >> 4;
        int cl  = ch0 & 15;
        int4 raw = *(const int4*)(xt + ((size_t)(b * G_ + g) * HW_ +
                                        (size_t)(yc * W_ + xc)) * CG_ + cl);
        if (!ok) raw = make_int4(0, 0, 0, 0);
        short8 bfr = *(short8*)&raw;

        const short8* w = wm + cc * 192;
        m0 = __builtin_amdgcn_mfma_f32_16x16x32_bf16(w[lane],       bfr, m0, 0, 0, 0);
        m1 = __builtin_amdgcn_mfma_f32_16x16x32_bf16(w[64 + lane],  bfr, m1, 0, 0, 0);
        m2 = __builtin_amdgcn_mfma_f32_16x16x32_bf16(w[128 + lane], bfr, m2, 0, 0, 0);
    }

    float* ml = &modl[wave][0][0];
#pragma unroll
    for (int reg = 0; reg < 4; ++reg) {
        int j0 = quad * 4 + reg;
        ml[j0 * 16 + px]        = 2.0f * sigmoidf(m0[reg] + bm[j0]);
        ml[(16 + j0) * 16 + px] = 2.0f * sigmoidf(m1[reg] + bm[16 + j0]);
        if (32 + j0 < MODC_)
            ml[(32 + j0) * 16 + px] = 2.0f * sigmoidf(m2[reg] + bm[32 + j0]);
    }
    // no __syncthreads(): modl[wave] is wave-private; lgkmcnt orders LDS ops.

    // ---------------- phase B: deformable conv, software-pipelined ----------
    f32x4 acc0 = {}, acc1 = {}, acc2 = {}, acc3 = {};
    const float* offp = out_off + (size_t)b * OFFC_ * HW_ + p;
    const short8* wa  = (const short8*)wA_def;
    int qh    = quad >> 1;
    int cbase = (quad & 1) * 8;

    float oy[NCHUNK_], ox[NCHUNK_];
#pragma unroll
    for (int cc = 0; cc < NCHUNK_; ++cc) {
        int gk = cc * 2 + qh;
        int g  = gk / 9, kk = gk - g * 9;
        oy[cc] = offp[(size_t)(g * 18 + kk * 2) * HW_];
        ox[cc] = offp[(size_t)(g * 18 + kk * 2 + 1) * HW_];
    }

    int4  G[2][4];
    float cw[2][4];

    PREPB(0, 0);
#pragma unroll
    for (int cc = 0; cc < NCHUNK_ - 1; ++cc) {
        PREPB(cc + 1, (cc + 1) & 1);
        CONSB(cc, cc & 1);
    }
    CONSB(NCHUNK_ - 1, (NCHUNK_ - 1) & 1);

    // D: row(o') = quad*4 + reg, col(px) = lane&15
    float* op = out + (size_t)b * O_ * HW_ + p;
#pragma unroll
    for (int reg = 0; reg < 4; ++reg) {
        int o0 = quad * 4 + reg;
        op[(size_t)o0 * HW_]        = acc0[reg];
        op[(size_t)(16 + o0) * HW_] = acc1[reg];
        op[(size_t)(32 + o0) * HW_] = acc2[reg];
        op[(size_t)(48 + o0) * HW_] = acc3[reg];
    }
}

extern "C" void kernel_launch(void* const* d_in, const int* in_sizes, int n_in,
                              void* d_out, int out_size, void* d_ws, size_t ws_size,
                              hipStream_t stream) {
    const float* warp = (const float*)d_in[0];
    const float* omap = (const float*)d_in[1];
    const float* wreg = (const float*)d_in[2];
    const float* wmod = (const float*)d_in[3];
    const float* bmod = (const float*)d_in[4];

    float* out     = (float*)d_out;                    // (4,64,160,160)
    float* out_off = out + (size_t)B_ * O_ * HW_;      // (4,72,160,160)

    unsigned short* xt = (unsigned short*)d_ws;                  // 13.1 MB bf16
    short* wA_def = (short*)(xt + (size_t)B_ * C_ * HW_);        // 36864 bf16
    short* wA_mod = wA_def + NCHUNK_ * 4 * 64 * 8;               // 27648 bf16

    hipLaunchKernelGGL(k_prep, dim3(8832), dim3(256), 0, stream,
                       warp, omap, wreg, wmod, xt, wA_def, wA_mod, out_off);
    hipLaunchKernelGGL(k_fused, dim3(1600), dim3(256), 0, stream,
                       xt, out_off, wA_mod, wA_def, bmod, out);
}